// Round 1
// baseline (1558.232 us; speedup 1.0000x reference)
//
#include <hip/hip_runtime.h>
#include <hip/hip_bf16.h>
#include <math.h>

// Problem constants
#define BB 16
#define NN 4096
#define CC 256
#define NC 768   // 3*C
#define KSZ 3

// ---------------------------------------------------------------------------
// Tiled fp32 GEMM: C[M x 768] = A[M x 256] @ B[256 x 768]
// 64x64 block tile, 256 threads, 4x4 per thread, BK=16.
// ---------------------------------------------------------------------------
#define BM 64
#define BN 64
#define BK 16

__global__ __launch_bounds__(256) void gemm_qkv(const float* __restrict__ A,
                                                const float* __restrict__ Bw,
                                                float* __restrict__ C) {
    const int K = CC;
    __shared__ float As[BK][BM];
    __shared__ float Bs[BK][BN];

    const int tid = threadIdx.x;
    const int tx = tid & 15;   // n-dir (0..15)
    const int ty = tid >> 4;   // m-dir (0..15)
    const int bn = blockIdx.x * BN;   // 0..768 step 64
    const int bm = blockIdx.y * BM;

    const float* Ab = A + (size_t)bm * K;

    // loader indices
    const int ar = tid >> 2;          // 0..63 (row in A tile)
    const int ac = (tid & 3) * 4;     // 0,4,8,12 (k within BK)
    const int bkk = tid >> 4;         // 0..15 (k row in B tile)
    const int bc = (tid & 15) * 4;    // 0..60 (col in B tile)

    float acc[4][4] = {};

    for (int kt = 0; kt < K; kt += BK) {
        float4 av = *(const float4*)(Ab + (size_t)ar * K + kt + ac);
        float4 bv = *(const float4*)(Bw + (size_t)(kt + bkk) * NC + bn + bc);
        As[ac + 0][ar] = av.x;
        As[ac + 1][ar] = av.y;
        As[ac + 2][ar] = av.z;
        As[ac + 3][ar] = av.w;
        *(float4*)&Bs[bkk][bc] = bv;
        __syncthreads();
#pragma unroll
        for (int kk = 0; kk < BK; ++kk) {
            float a[4], b[4];
#pragma unroll
            for (int i = 0; i < 4; ++i) a[i] = As[kk][ty * 4 + i];
#pragma unroll
            for (int j = 0; j < 4; ++j) b[j] = Bs[kk][tx * 4 + j];
#pragma unroll
            for (int i = 0; i < 4; ++i)
#pragma unroll
                for (int j = 0; j < 4; ++j) acc[i][j] += a[i] * b[j];
        }
        __syncthreads();
    }

#pragma unroll
    for (int i = 0; i < 4; ++i) {
        float4 o = make_float4(acc[i][0], acc[i][1], acc[i][2], acc[i][3]);
        *(float4*)(C + (size_t)(bm + ty * 4 + i) * NC + bn + tx * 4) = o;
    }
}

// ---------------------------------------------------------------------------
// Attention for one dilation over a chunk of rows.
// qkv: (rows, 768) with q=[0:256), k=[256:512), v=[512:768)
// combined: (rows, 256); if init, store (1/3)*out, else +=.
// One block (256 threads) per token row.
// ---------------------------------------------------------------------------
__global__ __launch_bounds__(256) void attn_kernel(const float* __restrict__ qkv,
                                                   float* __restrict__ combined,
                                                   int dilation, int init) {
    const int bn = blockIdx.x;            // row within chunk
    const int n = bn & (NN - 1);          // position within sequence
    const int base_row = bn - n;          // start row of this batch
    const int c = threadIdx.x;            // 0..255
    const float scale = 0.0625f;          // 256^-0.5

    const float* row = qkv + (size_t)bn * NC;
    const float qc = row[c];

    float dotp[KSZ];
    float vval[KSZ];
#pragma unroll
    for (int j = 0; j < KSZ; ++j) {
        int m = n + (j - 1) * dilation;   // pad = dilation, idx = n - d + j*d
        bool inb = (m >= 0) && (m < NN);
        int mc = inb ? m : 0;
        const float* krow = qkv + (size_t)(base_row + mc) * NC + CC;
        float kc = inb ? krow[c] : 0.0f;
        float vc = inb ? krow[CC + c] : 0.0f;
        dotp[j] = qc * kc;
        vval[j] = vc;
    }

    // reduce the 3 dot products across 256 threads
    __shared__ float red[KSZ][4];
    __shared__ float logits_s[KSZ];
    const int lane = threadIdx.x & 63;
    const int wid = threadIdx.x >> 6;
#pragma unroll
    for (int j = 0; j < KSZ; ++j) {
        float v = dotp[j];
#pragma unroll
        for (int off = 32; off > 0; off >>= 1) v += __shfl_down(v, off, 64);
        if (lane == 0) red[j][wid] = v;
    }
    __syncthreads();
    if (threadIdx.x < KSZ) {
        float s = red[threadIdx.x][0] + red[threadIdx.x][1] +
                  red[threadIdx.x][2] + red[threadIdx.x][3];
        logits_s[threadIdx.x] = s * scale;
    }
    __syncthreads();

    float l0 = logits_s[0], l1 = logits_s[1], l2 = logits_s[2];
    float mx = fmaxf(l0, fmaxf(l1, l2));
    float e0 = __expf(l0 - mx), e1 = __expf(l1 - mx), e2 = __expf(l2 - mx);
    float inv = 1.0f / (e0 + e1 + e2);
    float outc = (e0 * vval[0] + e1 * vval[1] + e2 * vval[2]) * inv * (1.0f / 3.0f);

    float* dst = combined + (size_t)bn * CC + c;
    if (init) *dst = outc;
    else *dst += outc;
}

// ---------------------------------------------------------------------------
// In-place projection: io[r,:] = io[r,:] @ Wproj + bias
// Block owns 16 rows (safe in-place); thread c computes column c.
// ---------------------------------------------------------------------------
#define PROWS 16
__global__ __launch_bounds__(256) void proj_inplace(float* __restrict__ io,
                                                    const float* __restrict__ Wproj,
                                                    const float* __restrict__ bias) {
    __shared__ float rows[PROWS][CC];
    const int base = blockIdx.x * PROWS;
    const int c = threadIdx.x;

#pragma unroll
    for (int r = 0; r < PROWS; ++r)
        rows[r][c] = io[(size_t)(base + r) * CC + c];
    __syncthreads();

    float acc[PROWS];
    const float bc = bias[c];
#pragma unroll
    for (int r = 0; r < PROWS; ++r) acc[r] = bc;

    for (int k = 0; k < CC; ++k) {
        float w = Wproj[(size_t)k * CC + c];
#pragma unroll
        for (int r = 0; r < PROWS; ++r) acc[r] += rows[r][k] * w;
    }

#pragma unroll
    for (int r = 0; r < PROWS; ++r)
        io[(size_t)(base + r) * CC + c] = acc[r];
}

// ---------------------------------------------------------------------------
extern "C" void kernel_launch(void* const* d_in, const int* in_sizes, int n_in,
                              void* d_out, int out_size, void* d_ws, size_t ws_size,
                              hipStream_t stream) {
    const float* x = (const float*)d_in[0];      // (16, 4096, 256)
    const float* Wqkv = (const float*)d_in[1];   // (3, 256, 768)
    const float* Wproj = (const float*)d_in[2];  // (256, 256)
    const float* bproj = (const float*)d_in[3];  // (256,)
    float* out = (float*)d_out;                  // (16, 4096, 256)
    float* qkv_ws = (float*)d_ws;

    const int dilations[3] = {1, 2, 3};

    // Pick the largest batch-chunk whose qkv buffer fits in ws.
    int Bc = BB;
    while (Bc > 1 && (size_t)Bc * NN * NC * sizeof(float) > ws_size) Bc >>= 1;

    for (int i = 0; i < 3; ++i) {
        const float* Wi = Wqkv + (size_t)i * CC * NC;
        for (int b0 = 0; b0 < BB; b0 += Bc) {
            const int Mrows = Bc * NN;
            // qkv = x[b0:b0+Bc] @ Wqkv[i]
            dim3 ggrid(NC / BN, Mrows / BM);
            gemm_qkv<<<ggrid, 256, 0, stream>>>(x + (size_t)b0 * NN * CC, Wi, qkv_ws);
            // attention + accumulate into out
            attn_kernel<<<Mrows, 256, 0, stream>>>(qkv_ws,
                                                   out + (size_t)b0 * NN * CC,
                                                   dilations[i], i == 0 ? 1 : 0);
        }
    }

    // out = out @ Wproj + bproj (in place)
    proj_inplace<<<(BB * NN) / PROWS, 256, 0, stream>>>(out, Wproj, bproj);
}

// Round 2
// 558.623 us; speedup vs baseline: 2.7894x; 2.7894x over previous
//
#include <hip/hip_runtime.h>
#include <hip/hip_bf16.h>
#include <math.h>

// Problem constants
#define BB 16
#define NN 4096
#define CC 256
#define NC 768   // 3*C
#define KSZ 3

typedef __attribute__((ext_vector_type(8))) __bf16 bf16x8;
typedef __attribute__((ext_vector_type(4))) float f32x4;

__device__ __forceinline__ unsigned short f2bf(float f) {
    union { float f; unsigned int u; } v; v.f = f;
    unsigned int r = (v.u + 0x7FFFu + ((v.u >> 16) & 1u)) >> 16;
    return (unsigned short)r;
}
__device__ __forceinline__ float bf2f(unsigned short b) {
    union { unsigned int u; float f; } v; v.u = ((unsigned int)b) << 16;
    return v.f;
}

// ---------------------------------------------------------------------------
// fp32 -> bf16 bulk convert (x), 4 elems/thread
// ---------------------------------------------------------------------------
__global__ __launch_bounds__(256) void convert_x(const float4* __restrict__ in,
                                                 ushort4* __restrict__ out, int n4) {
    int i = blockIdx.x * 256 + threadIdx.x;
    if (i < n4) {
        float4 f = in[i];
        ushort4 o;
        o.x = f2bf(f.x); o.y = f2bf(f.y); o.z = f2bf(f.z); o.w = f2bf(f.w);
        out[i] = o;
    }
}

// ---------------------------------------------------------------------------
// Wqkv (3,256,768) fp32 -> Wt (3,768,256) bf16 (transposed, n-major)
// ---------------------------------------------------------------------------
__global__ __launch_bounds__(256) void convert_wt(const float* __restrict__ Wqkv,
                                                  unsigned short* __restrict__ Wt) {
    int e = blockIdx.x * 256 + threadIdx.x;    // < 3*768*256
    int i = e / (NC * CC);
    int rem = e - i * NC * CC;
    int n = rem >> 8;       // /256
    int k = rem & 255;
    Wt[e] = f2bf(Wqkv[(size_t)i * CC * NC + (size_t)k * NC + n]);
}

// ---------------------------------------------------------------------------
// bf16 MFMA GEMM: C[M x 768] = A[M x 256] @ B[256 x 768], B given transposed
// (Bt is 768 x 256, n-major). m97 structure: 128x128 tile, BK=32, 4 waves 2x2,
// global_load_lds width 16, ds_read_b128 fragments. Output bf16.
// ---------------------------------------------------------------------------
#define GL16(gp, lp) \
    __builtin_amdgcn_global_load_lds((const __attribute__((address_space(1))) void*)(gp), \
                                     (__attribute__((address_space(3))) void*)(lp), 16, 0, 0)

__global__ __launch_bounds__(256) void gemm_mfma(const unsigned short* __restrict__ A,
                                                 const unsigned short* __restrict__ Bt,
                                                 unsigned short* __restrict__ Cout) {
    __shared__ unsigned short As[128 * 32];
    __shared__ unsigned short Bs[128 * 32];

    const int tid = threadIdx.x;
    const int lane = tid & 63;
    const int wave = tid >> 6;
    const int q = lane >> 4;       // quad 0..3
    const int r16 = lane & 15;
    const int wm = (wave >> 1) * 64;
    const int wn = (wave & 1) * 64;
    const int bm = blockIdx.y * 128;
    const int bn = blockIdx.x * 128;

    f32x4 acc[4][4];
#pragma unroll
    for (int i = 0; i < 4; ++i)
#pragma unroll
        for (int j = 0; j < 4; ++j) acc[i][j] = {0.f, 0.f, 0.f, 0.f};

    // staging: 512 chunks of 16B per tile; thread covers e=tid and e=tid+256.
    const int e0 = tid, e1 = tid + 256;
    const unsigned short* gA0 = A + (size_t)(bm + (e0 >> 2)) * CC + (e0 & 3) * 8;
    const unsigned short* gA1 = A + (size_t)(bm + (e1 >> 2)) * CC + (e1 & 3) * 8;
    const unsigned short* gB0 = Bt + (size_t)(bn + (e0 >> 2)) * CC + (e0 & 3) * 8;
    const unsigned short* gB1 = Bt + (size_t)(bn + (e1 >> 2)) * CC + (e1 & 3) * 8;

    for (int kt = 0; kt < CC; kt += 32) {
        if (kt) __syncthreads();   // protect LDS from previous iter's readers
        GL16(gA0 + kt, As + e0 * 8);
        GL16(gA1 + kt, As + e1 * 8);
        GL16(gB0 + kt, Bs + e0 * 8);
        GL16(gB1 + kt, Bs + e1 * 8);
        __syncthreads();           // drain vmcnt (compiler inserts waitcnt)

        bf16x8 af[4], bf[4];
#pragma unroll
        for (int mi = 0; mi < 4; ++mi)
            af[mi] = *(const bf16x8*)(As + (wm + mi * 16 + r16) * 32 + q * 8);
#pragma unroll
        for (int ni = 0; ni < 4; ++ni)
            bf[ni] = *(const bf16x8*)(Bs + (wn + ni * 16 + r16) * 32 + q * 8);
#pragma unroll
        for (int mi = 0; mi < 4; ++mi)
#pragma unroll
            for (int ni = 0; ni < 4; ++ni)
                acc[mi][ni] = __builtin_amdgcn_mfma_f32_16x16x32_bf16(
                    af[mi], bf[ni], acc[mi][ni], 0, 0, 0);
    }

    // epilogue: C/D layout col=lane&15, row=quad*4+reg  (m89-verified)
#pragma unroll
    for (int mi = 0; mi < 4; ++mi) {
#pragma unroll
        for (int ni = 0; ni < 4; ++ni) {
            int row0 = bm + wm + mi * 16 + q * 4;
            int col = bn + wn + ni * 16 + r16;
#pragma unroll
            for (int r = 0; r < 4; ++r)
                Cout[(size_t)(row0 + r) * NC + col] = f2bf(acc[mi][ni][r]);
        }
    }
}

// ---------------------------------------------------------------------------
// Attention, wave-per-token. qkv bf16 (rows,768): q[0:256) k[256:512) v[512:768)
// combined fp32 (rows,256): init ? store : +=, scaled by 1/3.
// ---------------------------------------------------------------------------
__global__ __launch_bounds__(256) void attn_bf16(const unsigned short* __restrict__ qkv,
                                                 float* __restrict__ combined,
                                                 int dilation, int init) {
    const int wave = threadIdx.x >> 6;
    const int lane = threadIdx.x & 63;
    const int row = blockIdx.x * 4 + wave;   // token row within chunk
    const int n = row & (NN - 1);
    const int base_row = row - n;
    const int c4 = lane * 4;

    ushort4 qu = *(const ushort4*)(qkv + (size_t)row * NC + c4);
    float q0 = bf2f(qu.x), q1 = bf2f(qu.y), q2 = bf2f(qu.z), q3 = bf2f(qu.w);

    float dot[KSZ];
    float4 vv[KSZ];
#pragma unroll
    for (int j = 0; j < KSZ; ++j) {
        int m = n + (j - 1) * dilation;
        bool inb = (m >= 0) && (m < NN);
        int mc = inb ? m : 0;
        const unsigned short* kr = qkv + (size_t)(base_row + mc) * NC + CC + c4;
        ushort4 ku = *(const ushort4*)kr;
        ushort4 vu = *(const ushort4*)(kr + CC);
        float k0 = inb ? bf2f(ku.x) : 0.f;
        float k1 = inb ? bf2f(ku.y) : 0.f;
        float k2 = inb ? bf2f(ku.z) : 0.f;
        float k3 = inb ? bf2f(ku.w) : 0.f;
        vv[j].x = inb ? bf2f(vu.x) : 0.f;
        vv[j].y = inb ? bf2f(vu.y) : 0.f;
        vv[j].z = inb ? bf2f(vu.z) : 0.f;
        vv[j].w = inb ? bf2f(vu.w) : 0.f;
        dot[j] = q0 * k0 + q1 * k1 + q2 * k2 + q3 * k3;
    }

    // 64-lane butterfly reduce, 3 values interleaved
#pragma unroll
    for (int off = 1; off < 64; off <<= 1) {
        dot[0] += __shfl_xor(dot[0], off, 64);
        dot[1] += __shfl_xor(dot[1], off, 64);
        dot[2] += __shfl_xor(dot[2], off, 64);
    }

    const float scale = 0.0625f;   // 256^-0.5
    float l0 = dot[0] * scale, l1 = dot[1] * scale, l2 = dot[2] * scale;
    float mx = fmaxf(l0, fmaxf(l1, l2));
    float e0 = __expf(l0 - mx), e1 = __expf(l1 - mx), e2 = __expf(l2 - mx);
    float w = 1.0f / (3.0f * (e0 + e1 + e2));

    float4 o;
    o.x = (e0 * vv[0].x + e1 * vv[1].x + e2 * vv[2].x) * w;
    o.y = (e0 * vv[0].y + e1 * vv[1].y + e2 * vv[2].y) * w;
    o.z = (e0 * vv[0].z + e1 * vv[1].z + e2 * vv[2].z) * w;
    o.w = (e0 * vv[0].w + e1 * vv[1].w + e2 * vv[2].w) * w;

    float* dst = combined + (size_t)row * CC + c4;
    if (init) {
        *(float4*)dst = o;
    } else {
        float4 p = *(const float4*)dst;
        p.x += o.x; p.y += o.y; p.z += o.z; p.w += o.w;
        *(float4*)dst = p;
    }
}

// ---------------------------------------------------------------------------
// In-place projection: io[r,:] = io[r,:] @ Wproj + bias (fp32)
// ---------------------------------------------------------------------------
#define PROWS 16
__global__ __launch_bounds__(256) void proj_inplace(float* __restrict__ io,
                                                    const float* __restrict__ Wproj,
                                                    const float* __restrict__ bias) {
    __shared__ float rows[PROWS][CC];
    const int base = blockIdx.x * PROWS;
    const int c = threadIdx.x;

#pragma unroll
    for (int r = 0; r < PROWS; ++r)
        rows[r][c] = io[(size_t)(base + r) * CC + c];
    __syncthreads();

    float acc[PROWS];
    const float bc = bias[c];
#pragma unroll
    for (int r = 0; r < PROWS; ++r) acc[r] = bc;

    for (int k = 0; k < CC; ++k) {
        float w = Wproj[(size_t)k * CC + c];
#pragma unroll
        for (int r = 0; r < PROWS; ++r) acc[r] += rows[r][k] * w;
    }

#pragma unroll
    for (int r = 0; r < PROWS; ++r)
        io[(size_t)(base + r) * CC + c] = acc[r];
}

// ---------------------------------------------------------------------------
extern "C" void kernel_launch(void* const* d_in, const int* in_sizes, int n_in,
                              void* d_out, int out_size, void* d_ws, size_t ws_size,
                              hipStream_t stream) {
    const float* x = (const float*)d_in[0];      // (16, 4096, 256)
    const float* Wqkv = (const float*)d_in[1];   // (3, 256, 768)
    const float* Wproj = (const float*)d_in[2];  // (256, 256)
    const float* bproj = (const float*)d_in[3];  // (256,)
    float* out = (float*)d_out;                  // (16, 4096, 256)

    unsigned short* xb = (unsigned short*)d_ws;              // 16*4096*256 bf16
    unsigned short* Wt = xb + (size_t)BB * NN * CC;          // 3*768*256 bf16
    unsigned short* qkvb = Wt + (size_t)3 * NC * CC;         // chunk qkv bf16

    size_t fixed = ((size_t)BB * NN * CC + (size_t)3 * NC * CC) * sizeof(unsigned short);
    int Bc = BB;
    while (Bc > 1 && fixed + (size_t)Bc * NN * NC * sizeof(unsigned short) > ws_size)
        Bc >>= 1;

    const int n4 = BB * NN * CC / 4;
    convert_x<<<(n4 + 255) / 256, 256, 0, stream>>>((const float4*)x, (ushort4*)xb, n4);
    convert_wt<<<(3 * NC * CC) / 256, 256, 0, stream>>>(Wqkv, Wt);

    for (int i = 0; i < 3; ++i) {
        for (int b0 = 0; b0 < BB; b0 += Bc) {
            const int Mrows = Bc * NN;
            dim3 g(NC / 128, Mrows / 128);
            gemm_mfma<<<g, 256, 0, stream>>>(xb + (size_t)b0 * NN * CC,
                                             Wt + (size_t)i * NC * CC, qkvb);
            attn_bf16<<<Mrows / 4, 256, 0, stream>>>(qkvb, out + (size_t)b0 * NN * CC,
                                                     i + 1, i == 0 ? 1 : 0);
        }
    }

    proj_inplace<<<(BB * NN) / PROWS, 256, 0, stream>>>(out, Wproj, bproj);
}

// Round 3
// 353.612 us; speedup vs baseline: 4.4066x; 1.5798x over previous
//
#include <hip/hip_runtime.h>
#include <hip/hip_bf16.h>
#include <math.h>

// Problem constants
#define BB 16
#define NN 4096
#define CC 256
#define NC 768    // 3*C
#define NCA 2304  // 3 dilations * 3C  (columns of the fused qkv GEMM)
#define KSZ 3

typedef __attribute__((ext_vector_type(8))) __bf16 bf16x8;
typedef __attribute__((ext_vector_type(4))) float f32x4;

__device__ __forceinline__ unsigned short f2bf(float f) {
    union { float f; unsigned int u; } v; v.f = f;
    unsigned int r = (v.u + 0x7FFFu + ((v.u >> 16) & 1u)) >> 16;
    return (unsigned short)r;
}
__device__ __forceinline__ float bf2f(unsigned short b) {
    union { unsigned int u; float f; } v; v.u = ((unsigned int)b) << 16;
    return v.f;
}

// ---------------------------------------------------------------------------
// fp32 -> bf16 bulk convert (x), 4 elems/thread
// ---------------------------------------------------------------------------
__global__ __launch_bounds__(256) void convert_x(const float4* __restrict__ in,
                                                 ushort4* __restrict__ out, int n4) {
    int i = blockIdx.x * 256 + threadIdx.x;
    if (i < n4) {
        float4 f = in[i];
        ushort4 o;
        o.x = f2bf(f.x); o.y = f2bf(f.y); o.z = f2bf(f.z); o.w = f2bf(f.w);
        out[i] = o;
    }
}

// ---------------------------------------------------------------------------
// Wqkv (3,256,768) fp32 -> Wt (3*768, 256) bf16, n-major (concatenated).
// ---------------------------------------------------------------------------
__global__ __launch_bounds__(256) void convert_wt(const float* __restrict__ Wqkv,
                                                  unsigned short* __restrict__ Wt) {
    int e = blockIdx.x * 256 + threadIdx.x;    // < 3*768*256
    int i = e / (NC * CC);
    int rem = e - i * NC * CC;
    int n = rem >> 8;       // /256
    int k = rem & 255;
    Wt[e] = f2bf(Wqkv[(size_t)i * CC * NC + (size_t)k * NC + n]);
}

// ---------------------------------------------------------------------------
// Wproj (256,256) fp32 k-major -> Wpt (256,256) bf16 n-major
// ---------------------------------------------------------------------------
__global__ __launch_bounds__(256) void convert_wp(const float* __restrict__ Wproj,
                                                  unsigned short* __restrict__ Wpt) {
    int e = blockIdx.x * 256 + threadIdx.x;    // < 256*256
    int n = e >> 8;
    int k = e & 255;
    Wpt[e] = f2bf(Wproj[(size_t)k * CC + n]);
}

// ---------------------------------------------------------------------------
// bf16 MFMA GEMM (m97 structure): 128x128 tile, BK=32, 4 waves 2x2,
// global_load_lds width 16, ds_read_b128 fragments. K fixed = 256.
// ---------------------------------------------------------------------------
#define GL16(gp, lp) \
    __builtin_amdgcn_global_load_lds((const __attribute__((address_space(1))) void*)(gp), \
                                     (__attribute__((address_space(3))) void*)(lp), 16, 0, 0)

// qkv GEMM: Cout (M x 2304) bf16, stride NCA
__global__ __launch_bounds__(256) void gemm_qkv(const unsigned short* __restrict__ A,
                                                const unsigned short* __restrict__ Bt,
                                                unsigned short* __restrict__ Cout) {
    __shared__ unsigned short As[128 * 32];
    __shared__ unsigned short Bs[128 * 32];

    const int tid = threadIdx.x;
    const int lane = tid & 63;
    const int wave = tid >> 6;
    const int q = lane >> 4;
    const int r16 = lane & 15;
    const int wm = (wave >> 1) * 64;
    const int wn = (wave & 1) * 64;
    const int bm = blockIdx.y * 128;
    const int bn = blockIdx.x * 128;

    f32x4 acc[4][4];
#pragma unroll
    for (int i = 0; i < 4; ++i)
#pragma unroll
        for (int j = 0; j < 4; ++j) acc[i][j] = {0.f, 0.f, 0.f, 0.f};

    const int e0 = tid, e1 = tid + 256;
    const unsigned short* gA0 = A + (size_t)(bm + (e0 >> 2)) * CC + (e0 & 3) * 8;
    const unsigned short* gA1 = A + (size_t)(bm + (e1 >> 2)) * CC + (e1 & 3) * 8;
    const unsigned short* gB0 = Bt + (size_t)(bn + (e0 >> 2)) * CC + (e0 & 3) * 8;
    const unsigned short* gB1 = Bt + (size_t)(bn + (e1 >> 2)) * CC + (e1 & 3) * 8;

    for (int kt = 0; kt < CC; kt += 32) {
        if (kt) __syncthreads();
        GL16(gA0 + kt, As + e0 * 8);
        GL16(gA1 + kt, As + e1 * 8);
        GL16(gB0 + kt, Bs + e0 * 8);
        GL16(gB1 + kt, Bs + e1 * 8);
        __syncthreads();

        bf16x8 af[4], bfr[4];
#pragma unroll
        for (int mi = 0; mi < 4; ++mi)
            af[mi] = *(const bf16x8*)(As + (wm + mi * 16 + r16) * 32 + q * 8);
#pragma unroll
        for (int ni = 0; ni < 4; ++ni)
            bfr[ni] = *(const bf16x8*)(Bs + (wn + ni * 16 + r16) * 32 + q * 8);
#pragma unroll
        for (int mi = 0; mi < 4; ++mi)
#pragma unroll
            for (int ni = 0; ni < 4; ++ni)
                acc[mi][ni] = __builtin_amdgcn_mfma_f32_16x16x32_bf16(
                    af[mi], bfr[ni], acc[mi][ni], 0, 0, 0);
    }

#pragma unroll
    for (int mi = 0; mi < 4; ++mi) {
#pragma unroll
        for (int ni = 0; ni < 4; ++ni) {
            int row0 = bm + wm + mi * 16 + q * 4;
            int col = bn + wn + ni * 16 + r16;
#pragma unroll
            for (int r = 0; r < 4; ++r)
                Cout[(size_t)(row0 + r) * NCA + col] = f2bf(acc[mi][ni][r]);
        }
    }
}

// proj GEMM: out (M x 256) fp32 = comb @ Wpt^T + bias
__global__ __launch_bounds__(256) void gemm_proj(const unsigned short* __restrict__ A,
                                                 const unsigned short* __restrict__ Bt,
                                                 const float* __restrict__ bias,
                                                 float* __restrict__ Cout) {
    __shared__ unsigned short As[128 * 32];
    __shared__ unsigned short Bs[128 * 32];

    const int tid = threadIdx.x;
    const int lane = tid & 63;
    const int wave = tid >> 6;
    const int q = lane >> 4;
    const int r16 = lane & 15;
    const int wm = (wave >> 1) * 64;
    const int wn = (wave & 1) * 64;
    const int bm = blockIdx.y * 128;
    const int bn = blockIdx.x * 128;

    f32x4 acc[4][4];
#pragma unroll
    for (int i = 0; i < 4; ++i)
#pragma unroll
        for (int j = 0; j < 4; ++j) acc[i][j] = {0.f, 0.f, 0.f, 0.f};

    const int e0 = tid, e1 = tid + 256;
    const unsigned short* gA0 = A + (size_t)(bm + (e0 >> 2)) * CC + (e0 & 3) * 8;
    const unsigned short* gA1 = A + (size_t)(bm + (e1 >> 2)) * CC + (e1 & 3) * 8;
    const unsigned short* gB0 = Bt + (size_t)(bn + (e0 >> 2)) * CC + (e0 & 3) * 8;
    const unsigned short* gB1 = Bt + (size_t)(bn + (e1 >> 2)) * CC + (e1 & 3) * 8;

    for (int kt = 0; kt < CC; kt += 32) {
        if (kt) __syncthreads();
        GL16(gA0 + kt, As + e0 * 8);
        GL16(gA1 + kt, As + e1 * 8);
        GL16(gB0 + kt, Bs + e0 * 8);
        GL16(gB1 + kt, Bs + e1 * 8);
        __syncthreads();

        bf16x8 af[4], bfr[4];
#pragma unroll
        for (int mi = 0; mi < 4; ++mi)
            af[mi] = *(const bf16x8*)(As + (wm + mi * 16 + r16) * 32 + q * 8);
#pragma unroll
        for (int ni = 0; ni < 4; ++ni)
            bfr[ni] = *(const bf16x8*)(Bs + (wn + ni * 16 + r16) * 32 + q * 8);
#pragma unroll
        for (int mi = 0; mi < 4; ++mi)
#pragma unroll
            for (int ni = 0; ni < 4; ++ni)
                acc[mi][ni] = __builtin_amdgcn_mfma_f32_16x16x32_bf16(
                    af[mi], bfr[ni], acc[mi][ni], 0, 0, 0);
    }

#pragma unroll
    for (int mi = 0; mi < 4; ++mi) {
#pragma unroll
        for (int ni = 0; ni < 4; ++ni) {
            int row0 = bm + wm + mi * 16 + q * 4;
            int col = bn + wn + ni * 16 + r16;
            float bc = bias[col];
#pragma unroll
            for (int r = 0; r < 4; ++r)
                Cout[(size_t)(row0 + r) * CC + col] = acc[mi][ni][r] + bc;
        }
    }
}

// ---------------------------------------------------------------------------
// Fused attention over all 3 dilations, wave-per-token.
// qkv (rows, 2304) bf16: dilation i at cols [i*768, i*768+768) as q|k|v.
// comb (rows, 256) bf16 output (mean over dilations).
// ---------------------------------------------------------------------------
__global__ __launch_bounds__(256) void attn_fused(const unsigned short* __restrict__ qkv,
                                                  unsigned short* __restrict__ comb) {
    const int wave = threadIdx.x >> 6;
    const int lane = threadIdx.x & 63;
    const int row = blockIdx.x * 4 + wave;   // token row within chunk
    const int n = row & (NN - 1);
    const int base_row = row - n;
    const int c4 = lane * 4;

    float4 outacc = {0.f, 0.f, 0.f, 0.f};
    const float scale = 0.0625f;   // 256^-0.5

#pragma unroll
    for (int i = 0; i < 3; ++i) {
        const int d = i + 1;
        const unsigned short* qr = qkv + (size_t)row * NCA + i * NC + c4;
        ushort4 qu = *(const ushort4*)qr;
        float q0 = bf2f(qu.x), q1 = bf2f(qu.y), q2 = bf2f(qu.z), q3 = bf2f(qu.w);

        float dot[KSZ];
        float4 vv[KSZ];
#pragma unroll
        for (int j = 0; j < KSZ; ++j) {
            int m = n + (j - 1) * d;
            bool inb = (m >= 0) && (m < NN);
            int mc = inb ? m : 0;
            const unsigned short* kr =
                qkv + (size_t)(base_row + mc) * NCA + i * NC + CC + c4;
            ushort4 ku = *(const ushort4*)kr;
            ushort4 vu = *(const ushort4*)(kr + CC);
            float k0 = inb ? bf2f(ku.x) : 0.f;
            float k1 = inb ? bf2f(ku.y) : 0.f;
            float k2 = inb ? bf2f(ku.z) : 0.f;
            float k3 = inb ? bf2f(ku.w) : 0.f;
            vv[j].x = inb ? bf2f(vu.x) : 0.f;
            vv[j].y = inb ? bf2f(vu.y) : 0.f;
            vv[j].z = inb ? bf2f(vu.z) : 0.f;
            vv[j].w = inb ? bf2f(vu.w) : 0.f;
            dot[j] = q0 * k0 + q1 * k1 + q2 * k2 + q3 * k3;
        }

#pragma unroll
        for (int off = 1; off < 64; off <<= 1) {
            dot[0] += __shfl_xor(dot[0], off, 64);
            dot[1] += __shfl_xor(dot[1], off, 64);
            dot[2] += __shfl_xor(dot[2], off, 64);
        }

        float l0 = dot[0] * scale, l1 = dot[1] * scale, l2 = dot[2] * scale;
        float mx = fmaxf(l0, fmaxf(l1, l2));
        float e0 = __expf(l0 - mx), e1 = __expf(l1 - mx), e2 = __expf(l2 - mx);
        float w = 1.0f / (3.0f * (e0 + e1 + e2));

        outacc.x += (e0 * vv[0].x + e1 * vv[1].x + e2 * vv[2].x) * w;
        outacc.y += (e0 * vv[0].y + e1 * vv[1].y + e2 * vv[2].y) * w;
        outacc.z += (e0 * vv[0].z + e1 * vv[1].z + e2 * vv[2].z) * w;
        outacc.w += (e0 * vv[0].w + e1 * vv[1].w + e2 * vv[2].w) * w;
    }

    ushort4 o;
    o.x = f2bf(outacc.x); o.y = f2bf(outacc.y);
    o.z = f2bf(outacc.z); o.w = f2bf(outacc.w);
    *(ushort4*)(comb + (size_t)row * CC + c4) = o;
}

// ---------------------------------------------------------------------------
extern "C" void kernel_launch(void* const* d_in, const int* in_sizes, int n_in,
                              void* d_out, int out_size, void* d_ws, size_t ws_size,
                              hipStream_t stream) {
    const float* x = (const float*)d_in[0];      // (16, 4096, 256)
    const float* Wqkv = (const float*)d_in[1];   // (3, 256, 768)
    const float* Wproj = (const float*)d_in[2];  // (256, 256)
    const float* bproj = (const float*)d_in[3];  // (256,)
    float* out = (float*)d_out;                  // (16, 4096, 256)

    unsigned short* xb = (unsigned short*)d_ws;              // 16*4096*256
    unsigned short* Wt = xb + (size_t)BB * NN * CC;          // 3*768*256
    unsigned short* Wpt = Wt + (size_t)3 * NC * CC;          // 256*256
    unsigned short* comb = Wpt + (size_t)CC * CC;            // 16*4096*256
    unsigned short* qkvb = comb + (size_t)BB * NN * CC;      // Bc*4096*2304

    size_t fixed = ((size_t)BB * NN * CC * 2 + (size_t)3 * NC * CC +
                    (size_t)CC * CC) * sizeof(unsigned short);
    int Bc = BB;
    while (Bc > 1 && fixed + (size_t)Bc * NN * NCA * sizeof(unsigned short) > ws_size)
        Bc >>= 1;

    const int n4 = BB * NN * CC / 4;
    convert_x<<<(n4 + 255) / 256, 256, 0, stream>>>((const float4*)x, (ushort4*)xb, n4);
    convert_wt<<<(3 * NC * CC) / 256, 256, 0, stream>>>(Wqkv, Wt);
    convert_wp<<<(CC * CC) / 256, 256, 0, stream>>>(Wproj, Wpt);

    for (int b0 = 0; b0 < BB; b0 += Bc) {
        const int Mrows = Bc * NN;
        dim3 g(NCA / 128, Mrows / 128);
        gemm_qkv<<<g, 256, 0, stream>>>(xb + (size_t)b0 * NN * CC, Wt, qkvb);
        attn_fused<<<Mrows / 4, 256, 0, stream>>>(qkvb, comb + (size_t)b0 * NN * CC);
    }

    dim3 gp(CC / 128, (BB * NN) / 128);
    gemm_proj<<<gp, 256, 0, stream>>>(comb, Wpt, bproj, out);
}

// Round 4
// 296.551 us; speedup vs baseline: 5.2545x; 1.1924x over previous
//
#include <hip/hip_runtime.h>
#include <hip/hip_bf16.h>
#include <math.h>

// Problem constants
#define BB 16
#define NN 4096
#define CC 256
#define NC 768     // 3*C
#define MTOT (BB * NN)   // 65536 tokens

typedef __attribute__((ext_vector_type(8))) __bf16 bf16x8;
typedef __attribute__((ext_vector_type(4))) float f32x4;

__device__ __forceinline__ unsigned short f2bf(float f) {
    union { float f; unsigned int u; } v; v.f = f;
    unsigned int r = (v.u + 0x7FFFu + ((v.u >> 16) & 1u)) >> 16;
    return (unsigned short)r;
}
__device__ __forceinline__ float bf2f(unsigned short b) {
    union { unsigned int u; float f; } v; v.u = ((unsigned int)b) << 16;
    return v.f;
}

#define GL16(gp, lp) \
    __builtin_amdgcn_global_load_lds((const __attribute__((address_space(1))) void*)(gp), \
                                     (__attribute__((address_space(3))) void*)(lp), 16, 0, 0)

// ---------------------------------------------------------------------------
// Shared MFMA GEMM core (m97 structure + XOR bank-conflict swizzle).
// C[row,col] = sum_k A[row,k] * Bt[col,k];  128x128 tile, BK=32, 4 waves 2x2.
// LDS chunk e (16B) holds global (row=e>>2, kc=(e&3)^((row>>1)&3)); fragment
// reads apply the same swizzle -> max 2-way bank aliasing (free).
// ---------------------------------------------------------------------------
template<int KDIM>
__device__ __forceinline__ void gemm_tile(const unsigned short* __restrict__ A,
                                          const unsigned short* __restrict__ Bt,
                                          int bm, int bn,
                                          unsigned short* As, unsigned short* Bs,
                                          f32x4 (&acc)[4][4]) {
    const int tid = threadIdx.x;
    const int lane = tid & 63;
    const int wave = tid >> 6;
    const int q = lane >> 4;
    const int r16 = lane & 15;
    const int wm = (wave >> 1) * 64;
    const int wn = (wave & 1) * 64;

    const int e0 = tid, e1 = tid + 256;
    const int r0 = e0 >> 2, r1 = e1 >> 2;
    const int kc0 = (e0 & 3) ^ ((r0 >> 1) & 3);
    const int kc1 = (e1 & 3) ^ ((r1 >> 1) & 3);
    const unsigned short* gA0 = A + (size_t)(bm + r0) * KDIM + kc0 * 8;
    const unsigned short* gA1 = A + (size_t)(bm + r1) * KDIM + kc1 * 8;
    const unsigned short* gB0 = Bt + (size_t)(bn + r0) * KDIM + kc0 * 8;
    const unsigned short* gB1 = Bt + (size_t)(bn + r1) * KDIM + kc1 * 8;

    const int sw = (q ^ ((r16 >> 1) & 3)) * 8;   // swizzled k-chunk offset

    for (int kt = 0; kt < KDIM; kt += 32) {
        if (kt) __syncthreads();
        GL16(gA0 + kt, As + e0 * 8);
        GL16(gA1 + kt, As + e1 * 8);
        GL16(gB0 + kt, Bs + e0 * 8);
        GL16(gB1 + kt, Bs + e1 * 8);
        __syncthreads();

        bf16x8 af[4], bfr[4];
#pragma unroll
        for (int mi = 0; mi < 4; ++mi)
            af[mi] = *(const bf16x8*)(As + (wm + mi * 16 + r16) * 32 + sw);
#pragma unroll
        for (int ni = 0; ni < 4; ++ni)
            bfr[ni] = *(const bf16x8*)(Bs + (wn + ni * 16 + r16) * 32 + sw);
#pragma unroll
        for (int mi = 0; mi < 4; ++mi)
#pragma unroll
            for (int ni = 0; ni < 4; ++ni)
                acc[mi][ni] = __builtin_amdgcn_mfma_f32_16x16x32_bf16(
                    af[mi], bfr[ni], acc[mi][ni], 0, 0, 0);
    }
}

// bf16-output GEMM, optional z-batching via pointer strides, scaled by mult.
template<int KDIM, int NOUT>
__global__ __launch_bounds__(256) void gemm_bf16(const unsigned short* __restrict__ A,
                                                 const unsigned short* __restrict__ Bt,
                                                 unsigned short* __restrict__ Cout,
                                                 float mult, int zA, int zB, int zC) {
    __shared__ unsigned short As[128 * 32];
    __shared__ unsigned short Bs[128 * 32];
    A += (size_t)blockIdx.z * zA;
    Bt += (size_t)blockIdx.z * zB;
    Cout += (size_t)blockIdx.z * zC;

    f32x4 acc[4][4];
#pragma unroll
    for (int i = 0; i < 4; ++i)
#pragma unroll
        for (int j = 0; j < 4; ++j) acc[i][j] = {0.f, 0.f, 0.f, 0.f};

    gemm_tile<KDIM>(A, Bt, blockIdx.y * 128, blockIdx.x * 128, As, Bs, acc);

    const int lane = threadIdx.x & 63;
    const int wave = threadIdx.x >> 6;
    const int q = lane >> 4, r16 = lane & 15;
    const int wm = (wave >> 1) * 64, wn = (wave & 1) * 64;
#pragma unroll
    for (int mi = 0; mi < 4; ++mi) {
#pragma unroll
        for (int ni = 0; ni < 4; ++ni) {
            int row0 = blockIdx.y * 128 + wm + mi * 16 + q * 4;
            int col = blockIdx.x * 128 + wn + ni * 16 + r16;
#pragma unroll
            for (int r = 0; r < 4; ++r)
                Cout[(size_t)(row0 + r) * NOUT + col] = f2bf(acc[mi][ni][r] * mult);
        }
    }
}

// fp32-output GEMM with bias (the final projection).
template<int KDIM, int NOUT>
__global__ __launch_bounds__(256) void gemm_f32b(const unsigned short* __restrict__ A,
                                                 const unsigned short* __restrict__ Bt,
                                                 const float* __restrict__ bias,
                                                 float* __restrict__ Cout) {
    __shared__ unsigned short As[128 * 32];
    __shared__ unsigned short Bs[128 * 32];

    f32x4 acc[4][4];
#pragma unroll
    for (int i = 0; i < 4; ++i)
#pragma unroll
        for (int j = 0; j < 4; ++j) acc[i][j] = {0.f, 0.f, 0.f, 0.f};

    gemm_tile<KDIM>(A, Bt, blockIdx.y * 128, blockIdx.x * 128, As, Bs, acc);

    const int lane = threadIdx.x & 63;
    const int wave = threadIdx.x >> 6;
    const int q = lane >> 4, r16 = lane & 15;
    const int wm = (wave >> 1) * 64, wn = (wave & 1) * 64;
#pragma unroll
    for (int mi = 0; mi < 4; ++mi) {
#pragma unroll
        for (int ni = 0; ni < 4; ++ni) {
            int row0 = blockIdx.y * 128 + wm + mi * 16 + q * 4;
            int col = blockIdx.x * 128 + wn + ni * 16 + r16;
            float bc = bias[col];
#pragma unroll
            for (int r = 0; r < 4; ++r)
                Cout[(size_t)(row0 + r) * NOUT + col] = acc[mi][ni][r] + bc;
        }
    }
}

// ---------------------------------------------------------------------------
// Converters
// ---------------------------------------------------------------------------
__global__ __launch_bounds__(256) void convert_x(const float4* __restrict__ in,
                                                 ushort4* __restrict__ out, int n4) {
    int i = blockIdx.x * 256 + threadIdx.x;
    if (i < n4) {
        float4 f = in[i];
        ushort4 o;
        o.x = f2bf(f.x); o.y = f2bf(f.y); o.z = f2bf(f.z); o.w = f2bf(f.w);
        out[i] = o;
    }
}

// Split Wqkv (3,256,768) fp32 into bf16 Wqb/Wkb (3,256,256) and Wvs (768,256).
__global__ __launch_bounds__(256) void conv_w(const float* __restrict__ Wqkv,
                                              unsigned short* __restrict__ Wqb,
                                              unsigned short* __restrict__ Wkb,
                                              unsigned short* __restrict__ Wvs) {
    int t = blockIdx.x * 256 + threadIdx.x;    // < 3*256*768
    unsigned short v = f2bf(Wqkv[t]);
    int ic = t / NC;        // i*256 + c
    int col = t - ic * NC;
    if (col < 256)       Wqb[(size_t)ic * CC + col] = v;
    else if (col < 512)  Wkb[(size_t)ic * CC + col - 256] = v;
    else                 Wvs[(size_t)ic * CC + col - 512] = v;
}

// WprojT bf16: WpT[g*256+e] = Wproj[e,g]
__global__ __launch_bounds__(256) void conv_wp(const float* __restrict__ Wproj,
                                               unsigned short* __restrict__ WpT) {
    int t = blockIdx.x * 256 + threadIdx.x;    // < 65536
    int g = t >> 8, e = t & 255;
    WpT[t] = f2bf(Wproj[(size_t)e * CC + g]);
}

// ---------------------------------------------------------------------------
// Attention: logits from y·x, softmax, z = sum a_j * x[m_j]; Z in-place on Y.
// yz (MTOT, 768) bf16; xb (MTOT, 256) bf16. Wave-per-token.
// ---------------------------------------------------------------------------
__global__ __launch_bounds__(256) void attn_z(const unsigned short* __restrict__ xb,
                                              unsigned short* __restrict__ yz) {
    const int wave = threadIdx.x >> 6;
    const int lane = threadIdx.x & 63;
    const int row = blockIdx.x * 4 + wave;
    const int n = row & (NN - 1);
    const int c4 = lane * 4;

    // Load the 7 window rows x[n-3..n+3] (zero outside the sequence).
    float4 xw[7];
#pragma unroll
    for (int o = 0; o < 7; ++o) {
        int m = n + o - 3;
        bool inb = (m >= 0) && (m < NN);
        int mrow = inb ? (row + o - 3) : row;
        ushort4 u = *(const ushort4*)(xb + (size_t)mrow * CC + c4);
        xw[o].x = inb ? bf2f(u.x) : 0.f;
        xw[o].y = inb ? bf2f(u.y) : 0.f;
        xw[o].z = inb ? bf2f(u.z) : 0.f;
        xw[o].w = inb ? bf2f(u.w) : 0.f;
    }

    float4 yv[3];
    float dots[3][3];
#pragma unroll
    for (int i = 0; i < 3; ++i) {
        ushort4 yu = *(const ushort4*)(yz + (size_t)row * NC + i * CC + c4);
        yv[i].x = bf2f(yu.x); yv[i].y = bf2f(yu.y);
        yv[i].z = bf2f(yu.z); yv[i].w = bf2f(yu.w);
#pragma unroll
        for (int j = 0; j < 3; ++j) {
            const float4 xv = xw[3 + (j - 1) * (i + 1)];
            dots[i][j] = yv[i].x * xv.x + yv[i].y * xv.y +
                         yv[i].z * xv.z + yv[i].w * xv.w;
        }
    }

#pragma unroll
    for (int off = 1; off < 64; off <<= 1) {
#pragma unroll
        for (int i = 0; i < 3; ++i)
#pragma unroll
            for (int j = 0; j < 3; ++j)
                dots[i][j] += __shfl_xor(dots[i][j], off, 64);
    }

#pragma unroll
    for (int i = 0; i < 3; ++i) {
        // scale (C^-0.5) is folded into M_i, 1/3 into P_i.
        float l0 = dots[i][0], l1 = dots[i][1], l2 = dots[i][2];
        float mx = fmaxf(l0, fmaxf(l1, l2));
        float e0 = __expf(l0 - mx), e1 = __expf(l1 - mx), e2 = __expf(l2 - mx);
        float inv = 1.0f / (e0 + e1 + e2);
        float a0 = e0 * inv, a1 = e1 * inv, a2 = e2 * inv;

        const float4 x0 = xw[3 - (i + 1)];
        const float4 x1 = xw[3];
        const float4 x2 = xw[3 + (i + 1)];
        ushort4 o;
        o.x = f2bf(a0 * x0.x + a1 * x1.x + a2 * x2.x);
        o.y = f2bf(a0 * x0.y + a1 * x1.y + a2 * x2.y);
        o.z = f2bf(a0 * x0.z + a1 * x1.z + a2 * x2.z);
        o.w = f2bf(a0 * x0.w + a1 * x1.w + a2 * x2.w);
        *(ushort4*)(yz + (size_t)row * NC + i * CC + c4) = o;
    }
}

// ---------------------------------------------------------------------------
extern "C" void kernel_launch(void* const* d_in, const int* in_sizes, int n_in,
                              void* d_out, int out_size, void* d_ws, size_t ws_size,
                              hipStream_t stream) {
    const float* x = (const float*)d_in[0];      // (16, 4096, 256)
    const float* Wqkv = (const float*)d_in[1];   // (3, 256, 768)
    const float* Wproj = (const float*)d_in[2];  // (256, 256)
    const float* bproj = (const float*)d_in[3];  // (256,)
    float* out = (float*)d_out;                  // (16, 4096, 256)

    unsigned short* xb  = (unsigned short*)d_ws;           // 65536*256
    unsigned short* Wqb = xb + (size_t)MTOT * CC;          // 3*256*256
    unsigned short* Wkb = Wqb + (size_t)3 * CC * CC;
    unsigned short* Wvs = Wkb + (size_t)3 * CC * CC;       // (768,256)
    unsigned short* WpT = Wvs + (size_t)3 * CC * CC;       // (256,256)
    unsigned short* MtY = WpT + (size_t)CC * CC;           // (768,256)
    unsigned short* PtZ = MtY + (size_t)NC * CC;           // (256,768)
    unsigned short* YZ  = PtZ + (size_t)CC * NC;           // 65536*768

    const float scale = 0.0625f;   // 256^-0.5

    const int n4 = MTOT * CC / 4;
    convert_x<<<(n4 + 255) / 256, 256, 0, stream>>>((const float4*)x, (ushort4*)xb, n4);
    conv_w<<<(3 * CC * NC) / 256, 256, 0, stream>>>(Wqkv, Wqb, Wkb, Wvs);
    conv_wp<<<(CC * CC) / 256, 256, 0, stream>>>(Wproj, WpT);

    // MtY[i*256+c', c] = scale * sum_a Wk_i[c',a] Wq_i[c,a]  (= M_i[c,c'])
    gemm_bf16<CC, CC><<<dim3(2, 2, 3), 256, 0, stream>>>(
        Wkb, Wqb, MtY, scale, CC * CC, CC * CC, CC * CC);
    // PtZ[g, i*256+c] = (1/3) * sum_e Wproj[e,g] Wv_i[c,e]  (= P_i[c,g]/3)
    gemm_bf16<CC, NC><<<dim3(6, 2, 1), 256, 0, stream>>>(
        WpT, Wvs, PtZ, 1.0f / 3.0f, 0, 0, 0);

    // Y = X @ [M1 M2 M3]   (65536 x 768)
    gemm_bf16<CC, NC><<<dim3(6, MTOT / 128, 1), 256, 0, stream>>>(
        xb, MtY, YZ, 1.0f, 0, 0, 0);

    // attention -> Z in place over Y
    attn_z<<<MTOT / 4, 256, 0, stream>>>(xb, YZ);

    // out = Z @ [P1;P2;P3] + bias   (65536 x 256, fp32)
    gemm_f32b<NC, CC><<<dim3(2, MTOT / 128, 1), 256, 0, stream>>>(
        YZ, PtZ, bproj, out);
}

// Round 5
// 287.688 us; speedup vs baseline: 5.4164x; 1.0308x over previous
//
#include <hip/hip_runtime.h>
#include <hip/hip_bf16.h>
#include <math.h>

// Problem constants
#define BB 16
#define NN 4096
#define CC 256
#define NC 768     // 3*C
#define MTOT (BB * NN)   // 65536 tokens

typedef __attribute__((ext_vector_type(8))) __bf16 bf16x8;
typedef __attribute__((ext_vector_type(4))) float f32x4;

__device__ __forceinline__ unsigned short f2bf(float f) {
    union { float f; unsigned int u; } v; v.f = f;
    unsigned int r = (v.u + 0x7FFFu + ((v.u >> 16) & 1u)) >> 16;
    return (unsigned short)r;
}
__device__ __forceinline__ float bf2f(unsigned short b) {
    union { unsigned int u; float f; } v; v.u = ((unsigned int)b) << 16;
    return v.f;
}

#define GL16(gp, lp) \
    __builtin_amdgcn_global_load_lds((const __attribute__((address_space(1))) void*)(gp), \
                                     (__attribute__((address_space(3))) void*)(lp), 16, 0, 0)

// ---------------------------------------------------------------------------
// Generic MFMA GEMM core (m97 structure) — used only for tiny weight-prep
// GEMMs (M_i = scale*Wk Wq^T, P_i = (1/3) Wproj^T Wv).
// ---------------------------------------------------------------------------
template<int KDIM>
__device__ __forceinline__ void gemm_tile(const unsigned short* __restrict__ A,
                                          const unsigned short* __restrict__ Bt,
                                          int bm, int bn,
                                          unsigned short* As, unsigned short* Bs,
                                          f32x4 (&acc)[4][4]) {
    const int tid = threadIdx.x;
    const int lane = tid & 63;
    const int wave = tid >> 6;
    const int q = lane >> 4;
    const int r16 = lane & 15;
    const int wm = (wave >> 1) * 64;
    const int wn = (wave & 1) * 64;

    const int e0 = tid, e1 = tid + 256;
    const int r0 = e0 >> 2, r1 = e1 >> 2;
    const int kc0 = (e0 & 3) ^ ((r0 >> 1) & 3);
    const int kc1 = (e1 & 3) ^ ((r1 >> 1) & 3);
    const unsigned short* gA0 = A + (size_t)(bm + r0) * KDIM + kc0 * 8;
    const unsigned short* gA1 = A + (size_t)(bm + r1) * KDIM + kc1 * 8;
    const unsigned short* gB0 = Bt + (size_t)(bn + r0) * KDIM + kc0 * 8;
    const unsigned short* gB1 = Bt + (size_t)(bn + r1) * KDIM + kc1 * 8;

    const int sw = (q ^ ((r16 >> 1) & 3)) * 8;

    for (int kt = 0; kt < KDIM; kt += 32) {
        if (kt) __syncthreads();
        GL16(gA0 + kt, As + e0 * 8);
        GL16(gA1 + kt, As + e1 * 8);
        GL16(gB0 + kt, Bs + e0 * 8);
        GL16(gB1 + kt, Bs + e1 * 8);
        __syncthreads();

        bf16x8 af[4], bfr[4];
#pragma unroll
        for (int mi = 0; mi < 4; ++mi)
            af[mi] = *(const bf16x8*)(As + (wm + mi * 16 + r16) * 32 + sw);
#pragma unroll
        for (int ni = 0; ni < 4; ++ni)
            bfr[ni] = *(const bf16x8*)(Bs + (wn + ni * 16 + r16) * 32 + sw);
#pragma unroll
        for (int mi = 0; mi < 4; ++mi)
#pragma unroll
            for (int ni = 0; ni < 4; ++ni)
                acc[mi][ni] = __builtin_amdgcn_mfma_f32_16x16x32_bf16(
                    af[mi], bfr[ni], acc[mi][ni], 0, 0, 0);
    }
}

template<int KDIM, int NOUT>
__global__ __launch_bounds__(256) void gemm_bf16(const unsigned short* __restrict__ A,
                                                 const unsigned short* __restrict__ Bt,
                                                 unsigned short* __restrict__ Cout,
                                                 float mult, int zA, int zB, int zC) {
    __shared__ unsigned short As[128 * 32];
    __shared__ unsigned short Bs[128 * 32];
    A += (size_t)blockIdx.z * zA;
    Bt += (size_t)blockIdx.z * zB;
    Cout += (size_t)blockIdx.z * zC;

    f32x4 acc[4][4];
#pragma unroll
    for (int i = 0; i < 4; ++i)
#pragma unroll
        for (int j = 0; j < 4; ++j) acc[i][j] = {0.f, 0.f, 0.f, 0.f};

    gemm_tile<KDIM>(A, Bt, blockIdx.y * 128, blockIdx.x * 128, As, Bs, acc);

    const int lane = threadIdx.x & 63;
    const int wave = threadIdx.x >> 6;
    const int q = lane >> 4, r16 = lane & 15;
    const int wm = (wave >> 1) * 64, wn = (wave & 1) * 64;
#pragma unroll
    for (int mi = 0; mi < 4; ++mi) {
#pragma unroll
        for (int ni = 0; ni < 4; ++ni) {
            int row0 = blockIdx.y * 128 + wm + mi * 16 + q * 4;
            int col = blockIdx.x * 128 + wn + ni * 16 + r16;
#pragma unroll
            for (int r = 0; r < 4; ++r)
                Cout[(size_t)(row0 + r) * NOUT + col] = f2bf(acc[mi][ni][r] * mult);
        }
    }
}

// ---------------------------------------------------------------------------
// Converters
// ---------------------------------------------------------------------------
__global__ __launch_bounds__(256) void convert_x(const float4* __restrict__ in,
                                                 ushort4* __restrict__ out, int n4) {
    int i = blockIdx.x * 256 + threadIdx.x;
    if (i < n4) {
        float4 f = in[i];
        ushort4 o;
        o.x = f2bf(f.x); o.y = f2bf(f.y); o.z = f2bf(f.z); o.w = f2bf(f.w);
        out[i] = o;
    }
}

// Split Wqkv (3,256,768) fp32 into bf16 Wqb/Wkb (3,256,256) and Wvs (768,256).
__global__ __launch_bounds__(256) void conv_w(const float* __restrict__ Wqkv,
                                              unsigned short* __restrict__ Wqb,
                                              unsigned short* __restrict__ Wkb,
                                              unsigned short* __restrict__ Wvs) {
    int t = blockIdx.x * 256 + threadIdx.x;
    unsigned short v = f2bf(Wqkv[t]);
    int ic = t / NC;
    int col = t - ic * NC;
    if (col < 256)       Wqb[(size_t)ic * CC + col] = v;
    else if (col < 512)  Wkb[(size_t)ic * CC + col - 256] = v;
    else                 Wvs[(size_t)ic * CC + col - 512] = v;
}

// WprojT bf16: WpT[g*256+e] = Wproj[e,g]
__global__ __launch_bounds__(256) void conv_wp(const float* __restrict__ Wproj,
                                               unsigned short* __restrict__ WpT) {
    int t = blockIdx.x * 256 + threadIdx.x;
    int g = t >> 8, e = t & 255;
    WpT[t] = f2bf(Wproj[(size_t)e * CC + g]);
}

// ---------------------------------------------------------------------------
// MEGA kernel: per block of 64 tokens, for each dilation i:
//   Y_i = x @ M_i^T  (MFMA, -> LDS ybuf)
//   z_i = softmax(y_i . x_window) blended x_window  (in-place on ybuf)
//   oacc += z_i @ P_i  (MFMA, AGPR accumulate)
// Finally out = oacc + bias (fp32). Y/Z never touch HBM.
// LDS: xbuf 72x264 (38016B) + ybuf 64x264 (33792B) + bstage 8192B = 80000B
// -> 2 blocks/CU on gfx950 (160 KiB LDS).
// ---------------------------------------------------------------------------
__global__ __launch_bounds__(256, 2) void mega(const unsigned short* __restrict__ xb,
                                               const unsigned short* __restrict__ MtY,
                                               const unsigned short* __restrict__ PtZ,
                                               const float* __restrict__ bias,
                                               float* __restrict__ out) {
    __shared__ __align__(16) unsigned short xbuf[72 * 264];  // 33-chunk pitch (+16B pad)
    __shared__ __align__(16) unsigned short ybuf[64 * 264];
    __shared__ __align__(16) unsigned short bstage[4096];    // 8KB; also float part[768]

    const int tid = threadIdx.x;
    const int lane = tid & 63;
    const int wave = tid >> 6;
    const int q = lane >> 4;
    const int r16 = lane & 15;
    const int t0 = blockIdx.x * 64;

    // ---- stage x rows [t0-3, t0+69) (clamped; OOB masked later) ----
    for (int it = 0; it < 9; ++it) {
        int e = it * 256 + tid;          // 0..2303 = 72 rows * 32 chunks
        int r = e >> 5, c = e & 31;
        int gr = t0 - 3 + r;
        gr = gr < 0 ? 0 : (gr > MTOT - 1 ? MTOT - 1 : gr);
        float4 v = *(const float4*)(xb + (size_t)gr * CC + c * 8);
        *(float4*)(xbuf + r * 264 + c * 8) = v;
    }
    __syncthreads();

    // persistent x A-fragments: wave owns tokens [wave*16, wave*16+16)
    bf16x8 af[8];
#pragma unroll
    for (int kt = 0; kt < 8; ++kt)
        af[kt] = *(const bf16x8*)(xbuf + (3 + wave * 16 + r16) * 264 + (kt * 4 + q) * 8);

    f32x4 oacc[16];
#pragma unroll
    for (int j = 0; j < 16; ++j) oacc[j] = {0.f, 0.f, 0.f, 0.f};

    for (int i = 0; i < 3; ++i) {
        const int d = i + 1;

        // ===== Phase 1: Y = x @ M_i^T  (64 x 256 -> ybuf) =====
        for (int nh = 0; nh < 2; ++nh) {
            f32x4 yacc[8];
#pragma unroll
            for (int j = 0; j < 8; ++j) yacc[j] = {0.f, 0.f, 0.f, 0.f};
            for (int kt = 0; kt < 8; ++kt) {
                __syncthreads();      // bstage safe to overwrite
                {
                    int e = tid;
                    GL16(MtY + (size_t)(i * 256 + nh * 128 + (e & 127)) * CC +
                             kt * 32 + (e >> 7) * 8,
                         bstage + e * 8);
                    e = tid + 256;
                    GL16(MtY + (size_t)(i * 256 + nh * 128 + (e & 127)) * CC +
                             kt * 32 + (e >> 7) * 8,
                         bstage + e * 8);
                }
                __syncthreads();      // staged
#pragma unroll
                for (int nf = 0; nf < 8; ++nf) {
                    bf16x8 bf = *(const bf16x8*)(bstage + (q * 128 + nf * 16 + r16) * 8);
                    yacc[nf] = __builtin_amdgcn_mfma_f32_16x16x32_bf16(
                        af[kt], bf, yacc[nf], 0, 0, 0);
                }
            }
#pragma unroll
            for (int nf = 0; nf < 8; ++nf)
#pragma unroll
                for (int r = 0; r < 4; ++r)
                    ybuf[(wave * 16 + q * 4 + r) * 264 + nh * 128 + nf * 16 + r16] =
                        f2bf(yacc[nf][r]);
        }
        __syncthreads();   // y ready; bstage free

        // ===== Phase 2: attention (thread = token t x 64-ch segment) =====
        {
            const int t = lane;          // token 0..63
            const int seg = wave;        // channel segment
            const int ns = (t0 + t) & (NN - 1);
            const bool vlo = (ns - d) >= 0;
            const bool vhi = (ns + d) < NN;
            const unsigned short* yrow = ybuf + t * 264;
            const unsigned short* x0r = xbuf + (3 + t - d) * 264;
            const unsigned short* x1r = xbuf + (3 + t) * 264;
            const unsigned short* x2r = xbuf + (3 + t + d) * 264;

            float p0 = 0.f, p1 = 0.f, p2 = 0.f;
#pragma unroll
            for (int kk = 0; kk < 8; ++kk) {
                int co = (seg * 8 + kk) * 8;
                bf16x8 yv = *(const bf16x8*)(yrow + co);
                bf16x8 a0 = *(const bf16x8*)(x0r + co);
                bf16x8 a1 = *(const bf16x8*)(x1r + co);
                bf16x8 a2 = *(const bf16x8*)(x2r + co);
                const unsigned short* yp = (const unsigned short*)&yv;
                const unsigned short* u0 = (const unsigned short*)&a0;
                const unsigned short* u1 = (const unsigned short*)&a1;
                const unsigned short* u2 = (const unsigned short*)&a2;
#pragma unroll
                for (int e = 0; e < 8; ++e) {
                    float yf = bf2f(yp[e]);
                    p0 += yf * bf2f(u0[e]);
                    p1 += yf * bf2f(u1[e]);
                    p2 += yf * bf2f(u2[e]);
                }
            }
            float* part = (float*)bstage;
            int pb = (seg * 64 + t) * 3;
            part[pb] = p0; part[pb + 1] = p1; part[pb + 2] = p2;
            __syncthreads();   // partials ready (and all y reads complete)

            float l0 = 0.f, l1 = 0.f, l2 = 0.f;
#pragma unroll
            for (int s = 0; s < 4; ++s) {
                int b = (s * 64 + t) * 3;
                l0 += part[b]; l1 += part[b + 1]; l2 += part[b + 2];
            }
            if (!vlo) l0 = 0.f;        // padded-zero logits (matches reference)
            if (!vhi) l2 = 0.f;
            float mx = fmaxf(l0, fmaxf(l1, l2));
            float e0 = __expf(l0 - mx), e1 = __expf(l1 - mx), e2 = __expf(l2 - mx);
            float inv = 1.0f / (e0 + e1 + e2);
            float a0w = vlo ? e0 * inv : 0.f;
            float a1w = e1 * inv;
            float a2w = vhi ? e2 * inv : 0.f;

            unsigned short* zrow = ybuf + t * 264;
#pragma unroll
            for (int kk = 0; kk < 8; ++kk) {
                int co = (seg * 8 + kk) * 8;
                bf16x8 a0 = *(const bf16x8*)(x0r + co);
                bf16x8 a1 = *(const bf16x8*)(x1r + co);
                bf16x8 a2 = *(const bf16x8*)(x2r + co);
                const unsigned short* u0 = (const unsigned short*)&a0;
                const unsigned short* u1 = (const unsigned short*)&a1;
                const unsigned short* u2 = (const unsigned short*)&a2;
                unsigned short zs[8];
#pragma unroll
                for (int e = 0; e < 8; ++e)
                    zs[e] = f2bf(a0w * bf2f(u0[e]) + a1w * bf2f(u1[e]) +
                                 a2w * bf2f(u2[e]));
                *(float4*)(zrow + co) = *(const float4*)zs;
            }
        }

        // ===== Phase 3: oacc += z @ P_i =====
        for (int nh = 0; nh < 2; ++nh) {
            for (int kt = 0; kt < 8; ++kt) {
                __syncthreads();      // z visible; bstage safe to overwrite
                {
                    int e = tid;
                    GL16(PtZ + (size_t)(nh * 128 + (e & 127)) * NC +
                             i * 256 + kt * 32 + (e >> 7) * 8,
                         bstage + e * 8);
                    e = tid + 256;
                    GL16(PtZ + (size_t)(nh * 128 + (e & 127)) * NC +
                             i * 256 + kt * 32 + (e >> 7) * 8,
                         bstage + e * 8);
                }
                __syncthreads();
                bf16x8 a = *(const bf16x8*)(ybuf + (wave * 16 + r16) * 264 +
                                            (kt * 4 + q) * 8);
#pragma unroll
                for (int nf = 0; nf < 8; ++nf) {
                    bf16x8 bf = *(const bf16x8*)(bstage + (q * 128 + nf * 16 + r16) * 8);
                    oacc[nh * 8 + nf] = __builtin_amdgcn_mfma_f32_16x16x32_bf16(
                        a, bf, oacc[nh * 8 + nf], 0, 0, 0);
                }
            }
        }
        // next dilation's Y-phase loop-top barrier protects ybuf/bstage reuse
    }

    // ===== epilogue: out = oacc + bias (fp32) =====
#pragma unroll
    for (int nh = 0; nh < 2; ++nh)
#pragma unroll
        for (int nf = 0; nf < 8; ++nf) {
            int g = nh * 128 + nf * 16 + r16;
            float bc = bias[g];
            f32x4 v = oacc[nh * 8 + nf];
#pragma unroll
            for (int r = 0; r < 4; ++r)
                out[(size_t)(t0 + wave * 16 + q * 4 + r) * CC + g] = v[r] + bc;
        }
}

// ---------------------------------------------------------------------------
extern "C" void kernel_launch(void* const* d_in, const int* in_sizes, int n_in,
                              void* d_out, int out_size, void* d_ws, size_t ws_size,
                              hipStream_t stream) {
    const float* x = (const float*)d_in[0];      // (16, 4096, 256)
    const float* Wqkv = (const float*)d_in[1];   // (3, 256, 768)
    const float* Wproj = (const float*)d_in[2];  // (256, 256)
    const float* bproj = (const float*)d_in[3];  // (256,)
    float* out = (float*)d_out;                  // (16, 4096, 256)

    unsigned short* xb  = (unsigned short*)d_ws;           // 65536*256
    unsigned short* Wqb = xb + (size_t)MTOT * CC;          // 3*256*256
    unsigned short* Wkb = Wqb + (size_t)3 * CC * CC;
    unsigned short* Wvs = Wkb + (size_t)3 * CC * CC;       // (768,256)
    unsigned short* WpT = Wvs + (size_t)3 * CC * CC;       // (256,256)
    unsigned short* MtY = WpT + (size_t)CC * CC;           // (768,256)
    unsigned short* PtZ = MtY + (size_t)NC * CC;           // (256,768)

    const float scale = 0.0625f;   // 256^-0.5

    const int n4 = MTOT * CC / 4;
    convert_x<<<(n4 + 255) / 256, 256, 0, stream>>>((const float4*)x, (ushort4*)xb, n4);
    conv_w<<<(3 * CC * NC) / 256, 256, 0, stream>>>(Wqkv, Wqb, Wkb, Wvs);
    conv_wp<<<(CC * CC) / 256, 256, 0, stream>>>(Wproj, WpT);

    // MtY[i*256+c'][c] = scale * sum_a Wk_i[c',a] Wq_i[c,a]
    gemm_bf16<CC, CC><<<dim3(2, 2, 3), 256, 0, stream>>>(
        Wkb, Wqb, MtY, scale, CC * CC, CC * CC, CC * CC);
    // PtZ[g][i*256+c] = (1/3) * sum_e Wproj[e,g] Wv_i[c,e]
    gemm_bf16<CC, NC><<<dim3(6, 2, 1), 256, 0, stream>>>(
        WpT, Wvs, PtZ, 1.0f / 3.0f, 0, 0, 0);

    mega<<<MTOT / 64, 256, 0, stream>>>(xb, MtY, PtZ, bproj, out);
}